// Round 16
// baseline (361.527 us; speedup 1.0000x reference)
//
#include <hip/hip_runtime.h>
#include <hip/hip_bf16.h>

typedef __attribute__((ext_vector_type(8))) short bf16x8;
typedef __attribute__((ext_vector_type(4))) float f32x4;

#define GLOAD_LDS16(gptr, lptr) \
  __builtin_amdgcn_global_load_lds((const __attribute__((address_space(1))) void*)(gptr), \
                                   (__attribute__((address_space(3))) void*)(lptr), 16, 0, 0)

__device__ __forceinline__ unsigned short f2b(float f) {
  union { float f; unsigned u; } x; x.f = f;
  unsigned r = x.u + 0x7fffu + ((x.u >> 16) & 1u);
  return (unsigned short)(r >> 16);
}
__device__ __forceinline__ float b2f(unsigned short u) {
  union { unsigned u; float f; } x; x.u = ((unsigned)u) << 16;
  return x.f;
}
__device__ __forceinline__ unsigned cvt_pk_bf16(float lo, float hi) {
  unsigned d;
  asm("v_cvt_pk_bf16_f32 %0, %1, %2" : "=v"(d) : "v"(lo), "v"(hi));
  return d;
}

// ------- fused fp32->bf16 cast (x|W_qkv|W_out) + RoPE cos/sin table fill -------
__global__ void cast3_kernel(const float* __restrict__ x,
                             const float* __restrict__ wq,
                             const float* __restrict__ wo,
                             unsigned short* __restrict__ out,
                             float2* __restrict__ tab)
{
  const long n1 = 8388608L;    // M*C
  const long n2 = 20971520L;   // + N1*C
  const long nc = 25165824L;   // + C*C
  const long tid = (long)blockIdx.x * 256 + threadIdx.x;
  const long i = tid * 4;
  if (i < nc) {
    const float* src; long off;
    if (i < n1)      { src = x;  off = i; }
    else if (i < n2) { src = wq; off = i - n1; }
    else             { src = wo; off = i - n2; }
    const float4 v = *(const float4*)(src + off);
    ushort4 r;
    r.x = f2b(v.x); r.y = f2b(v.y); r.z = f2b(v.z); r.w = f2b(v.w);
    *(ushort4*)(out + i) = r;
  } else {
    const int k = (int)(tid - nc / 4);   // 0..131071 = [tt(11)|j(6)]
    const int tt = k >> 6, j = k & 63;
    const float inv = exp2f(-(float)j * 0.2076205059304602f);
    float sn, cs;
    sincosf((float)tt * inv, &sn, &cs);
    tab[k] = make_float2(cs, sn);
  }
}

// ---------------- GEMM 128x256, BK=32, 3-slot LDS (R8 core, frozen) ----------------
// MODE 1: plain f32 C write (out projection).
// MODE 2: fused QKV epilogue — table-based RoPE for q/k, direct-transposed V store.
template<int MODE>
__global__ __launch_bounds__(512, 4)
void gemm128(const unsigned short* __restrict__ A,
             const unsigned short* __restrict__ Bm,
             const float* __restrict__ bias,
             void* __restrict__ Cp,
             unsigned short* __restrict__ Qr,
             unsigned short* __restrict__ Kr,
             unsigned short* __restrict__ Vt,
             const float2* __restrict__ tab,
             int M, int N, int K)
{
  __shared__ __align__(16) char Lds[73728];   // 3 slots x (A 8KB | B 16KB)
  const int t  = threadIdx.x;
  const int l  = t & 63;
  const int w  = t >> 6;
  const int lr = l & 15;
  const int lkb = (l >> 4) << 4;
  const int wr = w >> 2;
  const int wc = w & 3;

  const int nwg = gridDim.x;
  const int wg  = (blockIdx.x & 7) * (nwg >> 3) + (blockIdx.x >> 3);
  const int NBN = N >> 8;
  const int bm = wg / NBN, bn = wg % NBN;

  const long K2 = (long)K * 2;
  const char* Ab = (const char*)A  + (long)(bm * 128) * K2;
  const char* Bb = (const char*)Bm + (long)(bn * 256) * K2;

  auto swz = [](int a) -> int { return a ^ (((a >> 7) & 3) << 4); };

  const int t16 = t << 4;
  const int da  = swz(t16);
  const long sa = (long)(da >> 6) * K2 + (da & 63);
  const int db0 = swz(t16), db1 = swz(8192 + t16);
  const long sb0 = (long)(db0 >> 6) * K2 + (db0 & 63);
  const long sb1 = (long)(db1 >> 6) * K2 + (db1 & 63);

  auto stage = [&](int g) {
    char* S = Lds + (g % 3) * 24576;
    const char* As = Ab + (long)g * 64;
    const char* Bs = Bb + (long)g * 64;
    GLOAD_LDS16(As + sa,  S + t16);
    GLOAD_LDS16(Bs + sb0, S + 8192 + t16);
    GLOAD_LDS16(Bs + sb1, S + 16384 + t16);
  };

  int aoff[4], boff[4];
#pragma unroll
  for (int mi = 0; mi < 4; ++mi) {
    const int a = ((wr * 64 + mi * 16 + lr) << 6) | lkb;
    aoff[mi] = swz(a);
  }
#pragma unroll
  for (int ni = 0; ni < 4; ++ni) {
    const int a = ((wc * 64 + ni * 16 + lr) << 6) | lkb;
    boff[ni] = 8192 + swz(a);
  }

  f32x4 acc[4][4] = {};
  const int NT = K >> 5;
  bf16x8 af[4], bfr[4];

  stage(0); stage(1);
  asm volatile("s_waitcnt vmcnt(3)" ::: "memory");
  __builtin_amdgcn_s_barrier();
  __builtin_amdgcn_sched_barrier(0);
#pragma unroll
  for (int mi = 0; mi < 4; ++mi) af[mi]  = *(const bf16x8*)(Lds + aoff[mi]);
#pragma unroll
  for (int ni = 0; ni < 4; ++ni) bfr[ni] = *(const bf16x8*)(Lds + boff[ni]);

  for (int tt = 0; tt < NT; ++tt) {
    if (tt + 2 < NT) stage(tt + 2);
    __builtin_amdgcn_s_setprio(1);
#pragma unroll
    for (int mi = 0; mi < 4; ++mi)
#pragma unroll
      for (int ni = 0; ni < 4; ++ni)
        acc[mi][ni] = __builtin_amdgcn_mfma_f32_16x16x32_bf16(af[mi], bfr[ni], acc[mi][ni], 0, 0, 0);
    __builtin_amdgcn_s_setprio(0);
    if (tt + 1 < NT) {
      if (tt + 2 < NT) asm volatile("s_waitcnt vmcnt(3)" ::: "memory");
      else             asm volatile("s_waitcnt vmcnt(0)" ::: "memory");
      __builtin_amdgcn_s_barrier();
      __builtin_amdgcn_sched_barrier(0);
      const char* S = Lds + ((tt + 1) % 3) * 24576;
#pragma unroll
      for (int mi = 0; mi < 4; ++mi) af[mi]  = *(const bf16x8*)(S + aoff[mi]);
#pragma unroll
      for (int ni = 0; ni < 4; ++ni) bfr[ni] = *(const bf16x8*)(S + boff[ni]);
    }
  }

  const int roff = (l >> 4) << 2;
  const int row0 = bm * 128 + wr * 64 + roff;
  const int col0 = bn * 256 + wc * 64 + lr;
  float bv[4];
#pragma unroll
  for (int ni = 0; ni < 4; ++ni) bv[ni] = bias ? bias[col0 + ni * 16] : 0.0f;

  if (MODE == 1) {
#pragma unroll
    for (int mi = 0; mi < 4; ++mi) {
#pragma unroll
      for (int r = 0; r < 4; ++r) {
        const long rb = (long)(row0 + mi * 16 + r) * N;
#pragma unroll
        for (int ni = 0; ni < 4; ++ni)
          ((float*)Cp)[rb + col0 + ni * 16] = acc[mi][ni][r] + bv[ni];
      }
    }
  } else {
    const float C1 = 0.08838834764831845f * 1.4426950408889634f;  // 1/sqrt(128)*log2e
    const int sec = col0 >> 11;          // block-uniform: 0=q, 1=k, 2=v
    const int cq0 = col0 & 2047;
    const int parity = col0 & 1;         // = lr&1
    int hh[4], dd[4], jj[4];
#pragma unroll
    for (int ni = 0; ni < 4; ++ni) {
      const int c = cq0 + ni * 16;
      hh[ni] = c >> 7;
      dd[ni] = c & 127;
      jj[ni] = dd[ni] >> 1;
    }
    if (sec == 2) {
      // direct-transposed V: acc[mi][ni][0..3] = 4 consecutive tt (tt0 % 4 == 0)
#pragma unroll
      for (int mi = 0; mi < 4; ++mi) {
        const int tt0 = row0 + mi * 16;
        const int b = tt0 >> 11, ttl = tt0 & 2047;
#pragma unroll
        for (int ni = 0; ni < 4; ++ni) {
          ushort4 pk;
          pk.x = f2b(acc[mi][ni][0] + bv[ni]);
          pk.y = f2b(acc[mi][ni][1] + bv[ni]);
          pk.z = f2b(acc[mi][ni][2] + bv[ni]);
          pk.w = f2b(acc[mi][ni][3] + bv[ni]);
          *(ushort4*)&Vt[((long)((b << 4) | hh[ni]) * 128 + dd[ni]) * 2048 + ttl] = pk;
        }
      }
    } else {
#pragma unroll
      for (int mi = 0; mi < 4; ++mi) {
#pragma unroll
        for (int r = 0; r < 4; ++r) {
          const int row = row0 + mi * 16 + r;
          const int b = row >> 11, tt = row & 2047;
#pragma unroll
          for (int ni = 0; ni < 4; ++ni) {
            const float val = acc[mi][ni][r] + bv[ni];
            const float pv = __shfl_xor(val, 1, 64);
            const float2 t2 = tab[tt * 64 + jj[ni]];
            const float outv = parity ? fmaf(pv, t2.y, val * t2.x)
                                      : fmaf(val, t2.x, -(pv * t2.y));
            const long addr = ((long)((b << 4) | hh[ni]) * 2048 + tt) * 128 + jj[ni] + (parity << 6);
            if (sec == 0) Qr[addr] = f2b(outv);
            else          Kr[addr] = f2b(outv * C1);
          }
        }
      }
    }
  }
}

// ---------------- causal flash attention: K-only LDS, V direct from L2 ----------------
// LDS = K dbuf 32KB -> 4 blocks/CU. One vmcnt(0)+barrier per tile. PV B-fragments
// read straight from Vt (B,H,D,T): wave = 16 rows x 64B = 16 full L2 lines, L2-hot.
__global__ __launch_bounds__(256, 4)
void attn_fwd(const unsigned short* __restrict__ Q,
              const unsigned short* __restrict__ Kg,
              const unsigned short* __restrict__ Vt,
              unsigned short* __restrict__ O, int T)
{
  __shared__ __align__(16) unsigned short Ks[2][64 * 128];
  const int t = threadIdx.x;
  const int w = t >> 6, l = t & 63;
  const int lr = l & 15;
  const int g  = l >> 4;
  const int g16 = g << 4;
  const int sw = (lr & 7) << 4;
  const int bh = blockIdx.x;
  const int qt = (gridDim.y - 1) - blockIdx.y;
  const int q0 = qt * 64 + w * 16;
  const long hbase = (long)bh * T * 128;
  const long hbase2 = hbase * 2;
  const long T2 = (long)T * 2;
  const int roff = g << 2;

  bf16x8 qf[4];
  const unsigned short* Qrow = Q + hbase + (long)(q0 + lr) * 128;
#pragma unroll
  for (int ds = 0; ds < 4; ++ds) qf[ds] = *(const bf16x8*)&Qrow[ds * 32 + (g16 >> 1)];

  // V base for this lane: rows nj*16+lr of (B,H,D,T), byte column g16
  const char* Vb = (const char*)Vt + ((long)bh * 128 + lr) * T2 + g16;

  f32x4 o[8] = {};
  float m = -INFINITY, lsum = 0.f;

  auto stageK = [&](int kt, int buf) {
#pragma unroll
    for (int c = 0; c < 4; ++c) {
      const int o2 = t * 16 + c * 4096;
      const int krow = o2 >> 8, kcb = o2 & 255;
      GLOAD_LDS16((const char*)Kg + hbase2 + (long)kt * 16384 + krow * 256 + (kcb ^ ((krow & 7) << 4)),
                  (char*)Ks[buf] + o2);
    }
  };

  const int ntile = qt + 1;
  stageK(0, 0);
  asm volatile("s_waitcnt vmcnt(0)" ::: "memory");
  __builtin_amdgcn_s_barrier();

  for (int kt = 0; kt < ntile; ++kt) {
    const int cur = kt & 1;
    if (kt + 1 < ntile) stageK(kt + 1, cur ^ 1);

    const char* KsB = (const char*)Ks[cur];

    // S^T (exp2 domain, K pre-scaled): s[tj] = S[kv = kt*64+tj*16+4g+r][q = q0+lr]
    f32x4 s[4] = {};
    __builtin_amdgcn_s_setprio(1);
#pragma unroll
    for (int tj = 0; tj < 4; ++tj)
#pragma unroll
      for (int ds = 0; ds < 4; ++ds) {
        bf16x8 kf = *(const bf16x8*)(KsB + (tj * 16 + lr) * 256 + ((ds * 64 + g16) ^ sw));
        s[tj] = __builtin_amdgcn_mfma_f32_16x16x32_bf16(kf, qf[ds], s[tj], 0, 0, 0);
      }
    __builtin_amdgcn_s_setprio(0);

    if (kt == qt) {
#pragma unroll
      for (int tj = 0; tj < 4; ++tj)
#pragma unroll
        for (int r = 0; r < 4; ++r)
          if (kt * 64 + tj * 16 + 4 * g + r > q0 + lr) s[tj][r] = -INFINITY;
    }

    float pmax = -INFINITY;
#pragma unroll
    for (int tj = 0; tj < 4; ++tj)
#pragma unroll
      for (int r = 0; r < 4; ++r) pmax = fmaxf(pmax, s[tj][r]);
    pmax = fmaxf(pmax, __shfl_xor(pmax, 16, 64));
    pmax = fmaxf(pmax, __shfl_xor(pmax, 32, 64));

    const bool need = !__all(pmax - m <= 8.0f);
    float corr = 1.0f;
    if (need) {
      const float mn = fmaxf(m, pmax);
      corr = exp2f(m - mn);
      m = mn;
    }

    float p[4][4];
    float rs = 0.f;
#pragma unroll
    for (int tj = 0; tj < 4; ++tj)
#pragma unroll
      for (int r = 0; r < 4; ++r) {
        const float pv = exp2f(s[tj][r] - m);
        p[tj][r] = pv;
        rs += pv;
      }
    rs += __shfl_xor(rs, 16, 64);
    rs += __shfl_xor(rs, 32, 64);
    lsum = lsum * corr + rs;

    unsigned D8[4][2];
#pragma unroll
    for (int tj = 0; tj < 4; ++tj) {
      D8[tj][0] = cvt_pk_bf16(p[tj][0], p[tj][1]);
      D8[tj][1] = cvt_pk_bf16(p[tj][2], p[tj][3]);
    }

    if (need) {
      float corrj[4];
#pragma unroll
      for (int j = 0; j < 4; ++j) corrj[j] = __shfl(corr, roff + j, 64);
#pragma unroll
      for (int nj = 0; nj < 8; ++nj)
#pragma unroll
        for (int j = 0; j < 4; ++j) o[nj][j] *= corrj[j];
    }

    // PV: P A-frags in-register; V B-frags direct from global (L2-hot)
    const char* Vkt = Vb + (long)kt * 128;
    __builtin_amdgcn_s_setprio(1);
#pragma unroll
    for (int ks = 0; ks < 2; ++ks) {
      union { unsigned u[4]; bf16x8 v; } pfu;
#pragma unroll
      for (int k2 = 0; k2 < 4; ++k2) {
        const int src = lr | ((2 * (g & 1) + (k2 >> 1)) << 4);
        const unsigned dwA = __shfl(D8[2 * ks][k2 & 1], src, 64);
        const unsigned dwB = __shfl(D8[2 * ks + 1][k2 & 1], src, 64);
        pfu.u[k2] = (g & 2) ? dwB : dwA;
      }
#pragma unroll
      for (int nj = 0; nj < 8; ++nj) {
        bf16x8 vf = *(const bf16x8*)(Vkt + (long)(nj * 16) * T2 + ks * 64);
        o[nj] = __builtin_amdgcn_mfma_f32_16x16x32_bf16(pfu.v, vf, o[nj], 0, 0, 0);
      }
    }
    __builtin_amdgcn_s_setprio(0);

    // drain K(t+1) prefetch (vf already retired); all waves done with Ks[cur]
    asm volatile("s_waitcnt vmcnt(0)" ::: "memory");
    __builtin_amdgcn_s_barrier();
    __builtin_amdgcn_sched_barrier(0);
  }

  const float inv = 1.0f / lsum;
  float invj[4];
#pragma unroll
  for (int j = 0; j < 4; ++j) invj[j] = __shfl(inv, roff + j, 64);
  const int b = bh >> 4, h = bh & 15;
#pragma unroll
  for (int nj = 0; nj < 8; ++nj)
#pragma unroll
    for (int j = 0; j < 4; ++j) {
      const int q = q0 + roff + j;
      const int d = nj * 16 + lr;
      O[(long)(b * T + q) * 2048 + h * 128 + d] = f2b(o[nj][j] * invj[j]);
    }
}

// ---------------- launch ----------------
extern "C" void kernel_launch(void* const* d_in, const int* in_sizes, int n_in,
                              void* d_out, int out_size, void* d_ws, size_t ws_size,
                              hipStream_t stream)
{
  const int B = 2, T = 2048, C = 2048;
  const int M = B * T;        // 4096
  const int N1 = 3 * C;       // 6144
  const float* x    = (const float*)d_in[0];
  const float* Wqkv = (const float*)d_in[1];
  const float* bqkv = (const float*)d_in[2];
  const float* Wout = (const float*)d_in[3];
  const float* bout = (const float*)d_in[4];
  float* out = (float*)d_out;

  char* p = (char*)d_ws;
  unsigned short* xb    = (unsigned short*)p; p += (size_t)M * C * 2;
  unsigned short* wqkvb = (unsigned short*)p; p += (size_t)N1 * C * 2;
  unsigned short* woutb = (unsigned short*)p; p += (size_t)C * C * 2;
  unsigned short* Qr    = (unsigned short*)p; p += (size_t)M * C * 2;
  unsigned short* Kr    = (unsigned short*)p; p += (size_t)M * C * 2;
  unsigned short* Vt    = (unsigned short*)p; p += (size_t)M * C * 2;
  float2*         tab   = (float2*)p;         p += (size_t)T * 64 * sizeof(float2);
  unsigned short* Ob    = xb;  // xb dead after QKV GEMM

  // cast (24576 blocks) + rope table fill (512 blocks)
  cast3_kernel<<<24576 + 512, 256, 0, stream>>>(x, Wqkv, Wout, xb, tab);

  // QKV GEMM with fused table-RoPE/scale + direct-transposed V epilogue
  gemm128<2><<<dim3((M / 128) * (N1 / 256)), 512, 0, stream>>>(
      xb, wqkvb, bqkv, nullptr, Qr, Kr, Vt, tab, M, N1, C);

  attn_fwd<<<dim3(32, T / 64), 256, 0, stream>>>(Qr, Kr, Vt, Ob, T);

  gemm128<1><<<dim3((M / 128) * (C / 256)), 512, 0, stream>>>(
      Ob, woutb, bout, out, nullptr, nullptr, nullptr, nullptr, M, C, C);
}

// Round 17
// 272.000 us; speedup vs baseline: 1.3291x; 1.3291x over previous
//
#include <hip/hip_runtime.h>
#include <hip/hip_bf16.h>

typedef __attribute__((ext_vector_type(8))) short bf16x8;
typedef __attribute__((ext_vector_type(4))) float f32x4;

#define GLOAD_LDS16(gptr, lptr) \
  __builtin_amdgcn_global_load_lds((const __attribute__((address_space(1))) void*)(gptr), \
                                   (__attribute__((address_space(3))) void*)(lptr), 16, 0, 0)

__device__ __forceinline__ unsigned short f2b(float f) {
  union { float f; unsigned u; } x; x.f = f;
  unsigned r = x.u + 0x7fffu + ((x.u >> 16) & 1u);
  return (unsigned short)(r >> 16);
}
__device__ __forceinline__ float b2f(unsigned short u) {
  union { unsigned u; float f; } x; x.u = ((unsigned)u) << 16;
  return x.f;
}
__device__ __forceinline__ unsigned cvt_pk_bf16(float lo, float hi) {
  unsigned d;
  asm("v_cvt_pk_bf16_f32 %0, %1, %2" : "=v"(d) : "v"(lo), "v"(hi));
  return d;
}

// ------- fused fp32->bf16 cast (x|W_qkv|W_out) + RoPE cos/sin table fill -------
__global__ void cast3_kernel(const float* __restrict__ x,
                             const float* __restrict__ wq,
                             const float* __restrict__ wo,
                             unsigned short* __restrict__ out,
                             float2* __restrict__ tab)
{
  const long n1 = 8388608L;    // M*C
  const long n2 = 20971520L;   // + N1*C
  const long nc = 25165824L;   // + C*C
  const long tid = (long)blockIdx.x * 256 + threadIdx.x;
  const long i = tid * 4;
  if (i < nc) {
    const float* src; long off;
    if (i < n1)      { src = x;  off = i; }
    else if (i < n2) { src = wq; off = i - n1; }
    else             { src = wo; off = i - n2; }
    const float4 v = *(const float4*)(src + off);
    ushort4 r;
    r.x = f2b(v.x); r.y = f2b(v.y); r.z = f2b(v.z); r.w = f2b(v.w);
    *(ushort4*)(out + i) = r;
  } else {
    const int k = (int)(tid - nc / 4);   // 0..131071 = [tt(11)|j(6)]
    const int tt = k >> 6, j = k & 63;
    const float inv = exp2f(-(float)j * 0.2076205059304602f);
    float sn, cs;
    sincosf((float)tt * inv, &sn, &cs);
    tab[k] = make_float2(cs, sn);
  }
}

// ---------------- GEMM 128x256, BK=32, 3-slot LDS (R8 core, frozen) ----------------
// MODE 1: plain f32 C write (out projection).
// MODE 2: fused QKV epilogue — table-based RoPE for q/k, direct-transposed V store.
template<int MODE>
__global__ __launch_bounds__(512, 4)
void gemm128(const unsigned short* __restrict__ A,
             const unsigned short* __restrict__ Bm,
             const float* __restrict__ bias,
             void* __restrict__ Cp,
             unsigned short* __restrict__ Qr,
             unsigned short* __restrict__ Kr,
             unsigned short* __restrict__ Vt,
             const float2* __restrict__ tab,
             int M, int N, int K)
{
  __shared__ __align__(16) char Lds[73728];   // 3 slots x (A 8KB | B 16KB)
  const int t  = threadIdx.x;
  const int l  = t & 63;
  const int w  = t >> 6;
  const int lr = l & 15;
  const int lkb = (l >> 4) << 4;
  const int wr = w >> 2;
  const int wc = w & 3;

  const int nwg = gridDim.x;
  const int wg  = (blockIdx.x & 7) * (nwg >> 3) + (blockIdx.x >> 3);
  const int NBN = N >> 8;
  const int bm = wg / NBN, bn = wg % NBN;

  const long K2 = (long)K * 2;
  const char* Ab = (const char*)A  + (long)(bm * 128) * K2;
  const char* Bb = (const char*)Bm + (long)(bn * 256) * K2;

  auto swz = [](int a) -> int { return a ^ (((a >> 7) & 3) << 4); };

  const int t16 = t << 4;
  const int da  = swz(t16);
  const long sa = (long)(da >> 6) * K2 + (da & 63);
  const int db0 = swz(t16), db1 = swz(8192 + t16);
  const long sb0 = (long)(db0 >> 6) * K2 + (db0 & 63);
  const long sb1 = (long)(db1 >> 6) * K2 + (db1 & 63);

  auto stage = [&](int g) {
    char* S = Lds + (g % 3) * 24576;
    const char* As = Ab + (long)g * 64;
    const char* Bs = Bb + (long)g * 64;
    GLOAD_LDS16(As + sa,  S + t16);
    GLOAD_LDS16(Bs + sb0, S + 8192 + t16);
    GLOAD_LDS16(Bs + sb1, S + 16384 + t16);
  };

  int aoff[4], boff[4];
#pragma unroll
  for (int mi = 0; mi < 4; ++mi) {
    const int a = ((wr * 64 + mi * 16 + lr) << 6) | lkb;
    aoff[mi] = swz(a);
  }
#pragma unroll
  for (int ni = 0; ni < 4; ++ni) {
    const int a = ((wc * 64 + ni * 16 + lr) << 6) | lkb;
    boff[ni] = 8192 + swz(a);
  }

  f32x4 acc[4][4] = {};
  const int NT = K >> 5;
  bf16x8 af[4], bfr[4];

  stage(0); stage(1);
  asm volatile("s_waitcnt vmcnt(3)" ::: "memory");
  __builtin_amdgcn_s_barrier();
  __builtin_amdgcn_sched_barrier(0);
#pragma unroll
  for (int mi = 0; mi < 4; ++mi) af[mi]  = *(const bf16x8*)(Lds + aoff[mi]);
#pragma unroll
  for (int ni = 0; ni < 4; ++ni) bfr[ni] = *(const bf16x8*)(Lds + boff[ni]);

  for (int tt = 0; tt < NT; ++tt) {
    if (tt + 2 < NT) stage(tt + 2);
    __builtin_amdgcn_s_setprio(1);
#pragma unroll
    for (int mi = 0; mi < 4; ++mi)
#pragma unroll
      for (int ni = 0; ni < 4; ++ni)
        acc[mi][ni] = __builtin_amdgcn_mfma_f32_16x16x32_bf16(af[mi], bfr[ni], acc[mi][ni], 0, 0, 0);
    __builtin_amdgcn_s_setprio(0);
    if (tt + 1 < NT) {
      if (tt + 2 < NT) asm volatile("s_waitcnt vmcnt(3)" ::: "memory");
      else             asm volatile("s_waitcnt vmcnt(0)" ::: "memory");
      __builtin_amdgcn_s_barrier();
      __builtin_amdgcn_sched_barrier(0);
      const char* S = Lds + ((tt + 1) % 3) * 24576;
#pragma unroll
      for (int mi = 0; mi < 4; ++mi) af[mi]  = *(const bf16x8*)(S + aoff[mi]);
#pragma unroll
      for (int ni = 0; ni < 4; ++ni) bfr[ni] = *(const bf16x8*)(S + boff[ni]);
    }
  }

  const int roff = (l >> 4) << 2;
  const int row0 = bm * 128 + wr * 64 + roff;
  const int col0 = bn * 256 + wc * 64 + lr;
  float bv[4];
#pragma unroll
  for (int ni = 0; ni < 4; ++ni) bv[ni] = bias ? bias[col0 + ni * 16] : 0.0f;

  if (MODE == 1) {
#pragma unroll
    for (int mi = 0; mi < 4; ++mi) {
#pragma unroll
      for (int r = 0; r < 4; ++r) {
        const long rb = (long)(row0 + mi * 16 + r) * N;
#pragma unroll
        for (int ni = 0; ni < 4; ++ni)
          ((float*)Cp)[rb + col0 + ni * 16] = acc[mi][ni][r] + bv[ni];
      }
    }
  } else {
    const float C1 = 0.08838834764831845f * 1.4426950408889634f;  // 1/sqrt(128)*log2e
    const int sec = col0 >> 11;          // block-uniform: 0=q, 1=k, 2=v
    const int cq0 = col0 & 2047;
    const int parity = col0 & 1;         // = lr&1
    int hh[4], dd[4], jj[4];
#pragma unroll
    for (int ni = 0; ni < 4; ++ni) {
      const int c = cq0 + ni * 16;
      hh[ni] = c >> 7;
      dd[ni] = c & 127;
      jj[ni] = dd[ni] >> 1;
    }
    if (sec == 2) {
      // direct-transposed V: acc[mi][ni][0..3] = 4 consecutive tt (tt0 % 4 == 0)
#pragma unroll
      for (int mi = 0; mi < 4; ++mi) {
        const int tt0 = row0 + mi * 16;
        const int b = tt0 >> 11, ttl = tt0 & 2047;
#pragma unroll
        for (int ni = 0; ni < 4; ++ni) {
          ushort4 pk;
          pk.x = f2b(acc[mi][ni][0] + bv[ni]);
          pk.y = f2b(acc[mi][ni][1] + bv[ni]);
          pk.z = f2b(acc[mi][ni][2] + bv[ni]);
          pk.w = f2b(acc[mi][ni][3] + bv[ni]);
          *(ushort4*)&Vt[((long)((b << 4) | hh[ni]) * 128 + dd[ni]) * 2048 + ttl] = pk;
        }
      }
    } else {
#pragma unroll
      for (int mi = 0; mi < 4; ++mi) {
#pragma unroll
        for (int r = 0; r < 4; ++r) {
          const int row = row0 + mi * 16 + r;
          const int b = row >> 11, tt = row & 2047;
#pragma unroll
          for (int ni = 0; ni < 4; ++ni) {
            const float val = acc[mi][ni][r] + bv[ni];
            const float pv = __shfl_xor(val, 1, 64);
            const float2 t2 = tab[tt * 64 + jj[ni]];
            const float outv = parity ? fmaf(pv, t2.y, val * t2.x)
                                      : fmaf(val, t2.x, -(pv * t2.y));
            const long addr = ((long)((b << 4) | hh[ni]) * 2048 + tt) * 128 + jj[ni] + (parity << 6);
            if (sec == 0) Qr[addr] = f2b(outv);
            else          Kr[addr] = f2b(outv * C1);
          }
        }
      }
    }
  }
}

// ---------------- causal flash attention (R14 version, restored) ----------------
// K dbuf (32KB) + single-V (16KB) = 48KB -> 3 blocks/CU. Swapped QK^T (exp2 domain
// via pre-scaled K), in-reg softmax/P (cvt_pk+shfl), defer-max. Per tile:
// vmcnt(4)+barrier before PV (own V landed), __syncthreads at end, stage V(t+1) after.
__global__ __launch_bounds__(256)
void attn_fwd(const unsigned short* __restrict__ Q,
              const unsigned short* __restrict__ Kg,
              const unsigned short* __restrict__ Vt,
              unsigned short* __restrict__ O, int T)
{
  __shared__ __align__(16) unsigned short Ks[2][64 * 128];
  __shared__ __align__(16) unsigned short Vs[128 * 64];
  const int t = threadIdx.x;
  const int w = t >> 6, l = t & 63;
  const int lr = l & 15;
  const int g  = l >> 4;
  const int g16 = g << 4;
  const int sw = (lr & 7) << 4;
  const int bh = blockIdx.x;
  const int qt = (gridDim.y - 1) - blockIdx.y;
  const int q0 = qt * 64 + w * 16;
  const long hbase = (long)bh * T * 128;
  const long hbase2 = hbase * 2;
  const long T2 = (long)T * 2;
  const int roff = g << 2;

  bf16x8 qf[4];
  const unsigned short* Qrow = Q + hbase + (long)(q0 + lr) * 128;
#pragma unroll
  for (int ds = 0; ds < 4; ++ds) qf[ds] = *(const bf16x8*)&Qrow[ds * 32 + (g16 >> 1)];

  f32x4 o[8] = {};
  float m = -INFINITY, lsum = 0.f;

  auto stageK = [&](int kt, int buf) {
#pragma unroll
    for (int c = 0; c < 4; ++c) {
      const int o2 = t * 16 + c * 4096;
      const int krow = o2 >> 8, kcb = o2 & 255;
      GLOAD_LDS16((const char*)Kg + hbase2 + (long)kt * 16384 + krow * 256 + (kcb ^ ((krow & 7) << 4)),
                  (char*)Ks[buf] + o2);
    }
  };
  auto stageV = [&](int kt) {
#pragma unroll
    for (int c = 0; c < 4; ++c) {
      const int o2 = t * 16 + c * 4096;
      const int vrow = o2 >> 7, vcb = o2 & 127;
      GLOAD_LDS16((const char*)Vt + (long)(bh * 128 + vrow) * T2 + (long)kt * 128 + (vcb ^ ((vrow & 7) << 4)),
                  (char*)Vs + o2);
    }
  };

  const int ntile = qt + 1;
  stageK(0, 0);
  stageV(0);
  __syncthreads();

  for (int kt = 0; kt < ntile; ++kt) {
    const int cur = kt & 1;
    if (kt + 1 < ntile) stageK(kt + 1, cur ^ 1);

    const char* KsB = (const char*)Ks[cur];

    // S^T (exp2 domain, K pre-scaled): s[tj] = S[kv = kt*64+tj*16+4g+r][q = q0+lr]
    f32x4 s[4] = {};
    __builtin_amdgcn_s_setprio(1);
#pragma unroll
    for (int tj = 0; tj < 4; ++tj)
#pragma unroll
      for (int ds = 0; ds < 4; ++ds) {
        bf16x8 kf = *(const bf16x8*)(KsB + (tj * 16 + lr) * 256 + ((ds * 64 + g16) ^ sw));
        s[tj] = __builtin_amdgcn_mfma_f32_16x16x32_bf16(kf, qf[ds], s[tj], 0, 0, 0);
      }
    __builtin_amdgcn_s_setprio(0);

    if (kt == qt) {
#pragma unroll
      for (int tj = 0; tj < 4; ++tj)
#pragma unroll
        for (int r = 0; r < 4; ++r)
          if (kt * 64 + tj * 16 + 4 * g + r > q0 + lr) s[tj][r] = -INFINITY;
    }

    float pmax = -INFINITY;
#pragma unroll
    for (int tj = 0; tj < 4; ++tj)
#pragma unroll
      for (int r = 0; r < 4; ++r) pmax = fmaxf(pmax, s[tj][r]);
    pmax = fmaxf(pmax, __shfl_xor(pmax, 16, 64));
    pmax = fmaxf(pmax, __shfl_xor(pmax, 32, 64));

    const bool need = !__all(pmax - m <= 8.0f);
    float corr = 1.0f;
    if (need) {
      const float mn = fmaxf(m, pmax);
      corr = exp2f(m - mn);
      m = mn;
    }

    float p[4][4];
    float rs = 0.f;
#pragma unroll
    for (int tj = 0; tj < 4; ++tj)
#pragma unroll
      for (int r = 0; r < 4; ++r) {
        const float pv = exp2f(s[tj][r] - m);
        p[tj][r] = pv;
        rs += pv;
      }
    rs += __shfl_xor(rs, 16, 64);
    rs += __shfl_xor(rs, 32, 64);
    lsum = lsum * corr + rs;

    unsigned D8[4][2];
#pragma unroll
    for (int tj = 0; tj < 4; ++tj) {
      D8[tj][0] = cvt_pk_bf16(p[tj][0], p[tj][1]);
      D8[tj][1] = cvt_pk_bf16(p[tj][2], p[tj][3]);
    }

    if (need) {
      float corrj[4];
#pragma unroll
      for (int j = 0; j < 4; ++j) corrj[j] = __shfl(corr, roff + j, 64);
#pragma unroll
      for (int nj = 0; nj < 8; ++nj)
#pragma unroll
        for (int j = 0; j < 4; ++j) o[nj][j] *= corrj[j];
    }

    // own V loads landed (4 K-loads may remain in flight); all waves at barrier
    if (kt + 1 < ntile) asm volatile("s_waitcnt vmcnt(4)" ::: "memory");
    else                asm volatile("s_waitcnt vmcnt(0)" ::: "memory");
    __builtin_amdgcn_s_barrier();
    __builtin_amdgcn_sched_barrier(0);

    __builtin_amdgcn_s_setprio(1);
#pragma unroll
    for (int ks = 0; ks < 2; ++ks) {
      union { unsigned u[4]; bf16x8 v; } pfu;
#pragma unroll
      for (int k2 = 0; k2 < 4; ++k2) {
        const int src = lr | ((2 * (g & 1) + (k2 >> 1)) << 4);
        const unsigned dwA = __shfl(D8[2 * ks][k2 & 1], src, 64);
        const unsigned dwB = __shfl(D8[2 * ks + 1][k2 & 1], src, 64);
        pfu.u[k2] = (g & 2) ? dwB : dwA;
      }
#pragma unroll
      for (int nj = 0; nj < 8; ++nj) {
        bf16x8 vf = *(const bf16x8*)((const char*)Vs + (nj * 16 + lr) * 128 + ((ks * 64 + g16) ^ sw));
        o[nj] = __builtin_amdgcn_mfma_f32_16x16x32_bf16(pfu.v, vf, o[nj], 0, 0, 0);
      }
    }
    __builtin_amdgcn_s_setprio(0);

    __syncthreads();                       // all waves done with Vs + Ks[cur]
    if (kt + 1 < ntile) stageV(kt + 1);    // safe overwrite of single V buffer
  }

  const float inv = 1.0f / lsum;
  float invj[4];
#pragma unroll
  for (int j = 0; j < 4; ++j) invj[j] = __shfl(inv, roff + j, 64);
  const int b = bh >> 4, h = bh & 15;
#pragma unroll
  for (int nj = 0; nj < 8; ++nj)
#pragma unroll
    for (int j = 0; j < 4; ++j) {
      const int q = q0 + roff + j;
      const int d = nj * 16 + lr;
      O[(long)(b * T + q) * 2048 + h * 128 + d] = f2b(o[nj][j] * invj[j]);
    }
}

// ---------------- launch ----------------
extern "C" void kernel_launch(void* const* d_in, const int* in_sizes, int n_in,
                              void* d_out, int out_size, void* d_ws, size_t ws_size,
                              hipStream_t stream)
{
  const int B = 2, T = 2048, C = 2048;
  const int M = B * T;        // 4096
  const int N1 = 3 * C;       // 6144
  const float* x    = (const float*)d_in[0];
  const float* Wqkv = (const float*)d_in[1];
  const float* bqkv = (const float*)d_in[2];
  const float* Wout = (const float*)d_in[3];
  const float* bout = (const float*)d_in[4];
  float* out = (float*)d_out;

  char* p = (char*)d_ws;
  unsigned short* xb    = (unsigned short*)p; p += (size_t)M * C * 2;
  unsigned short* wqkvb = (unsigned short*)p; p += (size_t)N1 * C * 2;
  unsigned short* woutb = (unsigned short*)p; p += (size_t)C * C * 2;
  unsigned short* Qr    = (unsigned short*)p; p += (size_t)M * C * 2;
  unsigned short* Kr    = (unsigned short*)p; p += (size_t)M * C * 2;
  unsigned short* Vt    = (unsigned short*)p; p += (size_t)M * C * 2;
  float2*         tab   = (float2*)p;         p += (size_t)T * 64 * sizeof(float2);
  unsigned short* Ob    = xb;  // xb dead after QKV GEMM

  // cast (24576 blocks) + rope table fill (512 blocks)
  cast3_kernel<<<24576 + 512, 256, 0, stream>>>(x, Wqkv, Wout, xb, tab);

  // QKV GEMM with fused table-RoPE/scale + direct-transposed V epilogue
  gemm128<2><<<dim3((M / 128) * (N1 / 256)), 512, 0, stream>>>(
      xb, wqkvb, bqkv, nullptr, Qr, Kr, Vt, tab, M, N1, C);

  attn_fwd<<<dim3(32, T / 64), 256, 0, stream>>>(Qr, Kr, Vt, Ob, T);

  gemm128<1><<<dim3((M / 128) * (C / 256)), 512, 0, stream>>>(
      Ob, woutb, bout, out, nullptr, nullptr, nullptr, nullptr, M, C, C);
}

// Round 18
// 266.862 us; speedup vs baseline: 1.3547x; 1.0193x over previous
//
#include <hip/hip_runtime.h>
#include <hip/hip_bf16.h>

typedef __attribute__((ext_vector_type(8))) short bf16x8;
typedef __attribute__((ext_vector_type(4))) float f32x4;

#define GLOAD_LDS16(gptr, lptr) \
  __builtin_amdgcn_global_load_lds((const __attribute__((address_space(1))) void*)(gptr), \
                                   (__attribute__((address_space(3))) void*)(lptr), 16, 0, 0)

__device__ __forceinline__ unsigned short f2b(float f) {
  union { float f; unsigned u; } x; x.f = f;
  unsigned r = x.u + 0x7fffu + ((x.u >> 16) & 1u);
  return (unsigned short)(r >> 16);
}
__device__ __forceinline__ float b2f(unsigned short u) {
  union { unsigned u; float f; } x; x.u = ((unsigned)u) << 16;
  return x.f;
}
__device__ __forceinline__ unsigned cvt_pk_bf16(float lo, float hi) {
  unsigned d;
  asm("v_cvt_pk_bf16_f32 %0, %1, %2" : "=v"(d) : "v"(lo), "v"(hi));
  return d;
}

// ------- fused fp32->bf16 cast (x|W_qkv|W_out) + RoPE cos/sin table fill -------
__global__ void cast3_kernel(const float* __restrict__ x,
                             const float* __restrict__ wq,
                             const float* __restrict__ wo,
                             unsigned short* __restrict__ out,
                             float2* __restrict__ tab)
{
  const long n1 = 8388608L;    // M*C
  const long n2 = 20971520L;   // + N1*C
  const long nc = 25165824L;   // + C*C
  const long tid = (long)blockIdx.x * 256 + threadIdx.x;
  const long i = tid * 4;
  if (i < nc) {
    const float* src; long off;
    if (i < n1)      { src = x;  off = i; }
    else if (i < n2) { src = wq; off = i - n1; }
    else             { src = wo; off = i - n2; }
    const float4 v = *(const float4*)(src + off);
    ushort4 r;
    r.x = f2b(v.x); r.y = f2b(v.y); r.z = f2b(v.z); r.w = f2b(v.w);
    *(ushort4*)(out + i) = r;
  } else {
    const int k = (int)(tid - nc / 4);   // 0..131071 = [tt(11)|j(6)]
    const int tt = k >> 6, j = k & 63;
    const float inv = exp2f(-(float)j * 0.2076205059304602f);
    float sn, cs;
    sincosf((float)tt * inv, &sn, &cs);
    tab[k] = make_float2(cs, sn);
  }
}

// ---------------- GEMM 128x256, BK=32, 3-slot LDS (R8 core, frozen) ----------------
// MODE 1: plain f32 C write (out projection).
// MODE 2: fused QKV epilogue — table-based RoPE for q/k, direct-transposed V store.
//   Q/K use an INTERLEAVED d-layout (out[j]->d'=2j, out[64+j]->d'=2j+1): QK^T is
//   invariant under a shared d-permutation, and every lane then stores at its own
//   column c -> dense coalesced 2B stores. V/O stay in true d-space.
template<int MODE>
__global__ __launch_bounds__(512, 4)
void gemm128(const unsigned short* __restrict__ A,
             const unsigned short* __restrict__ Bm,
             const float* __restrict__ bias,
             void* __restrict__ Cp,
             unsigned short* __restrict__ Qr,
             unsigned short* __restrict__ Kr,
             unsigned short* __restrict__ Vt,
             const float2* __restrict__ tab,
             int M, int N, int K)
{
  __shared__ __align__(16) char Lds[73728];   // 3 slots x (A 8KB | B 16KB)
  const int t  = threadIdx.x;
  const int l  = t & 63;
  const int w  = t >> 6;
  const int lr = l & 15;
  const int lkb = (l >> 4) << 4;
  const int wr = w >> 2;
  const int wc = w & 3;

  const int nwg = gridDim.x;
  const int wg  = (blockIdx.x & 7) * (nwg >> 3) + (blockIdx.x >> 3);
  const int NBN = N >> 8;
  const int bm = wg / NBN, bn = wg % NBN;

  const long K2 = (long)K * 2;
  const char* Ab = (const char*)A  + (long)(bm * 128) * K2;
  const char* Bb = (const char*)Bm + (long)(bn * 256) * K2;

  auto swz = [](int a) -> int { return a ^ (((a >> 7) & 3) << 4); };

  const int t16 = t << 4;
  const int da  = swz(t16);
  const long sa = (long)(da >> 6) * K2 + (da & 63);
  const int db0 = swz(t16), db1 = swz(8192 + t16);
  const long sb0 = (long)(db0 >> 6) * K2 + (db0 & 63);
  const long sb1 = (long)(db1 >> 6) * K2 + (db1 & 63);

  auto stage = [&](int g) {
    char* S = Lds + (g % 3) * 24576;
    const char* As = Ab + (long)g * 64;
    const char* Bs = Bb + (long)g * 64;
    GLOAD_LDS16(As + sa,  S + t16);
    GLOAD_LDS16(Bs + sb0, S + 8192 + t16);
    GLOAD_LDS16(Bs + sb1, S + 16384 + t16);
  };

  int aoff[4], boff[4];
#pragma unroll
  for (int mi = 0; mi < 4; ++mi) {
    const int a = ((wr * 64 + mi * 16 + lr) << 6) | lkb;
    aoff[mi] = swz(a);
  }
#pragma unroll
  for (int ni = 0; ni < 4; ++ni) {
    const int a = ((wc * 64 + ni * 16 + lr) << 6) | lkb;
    boff[ni] = 8192 + swz(a);
  }

  f32x4 acc[4][4] = {};
  const int NT = K >> 5;
  bf16x8 af[4], bfr[4];

  stage(0); stage(1);
  asm volatile("s_waitcnt vmcnt(3)" ::: "memory");
  __builtin_amdgcn_s_barrier();
  __builtin_amdgcn_sched_barrier(0);
#pragma unroll
  for (int mi = 0; mi < 4; ++mi) af[mi]  = *(const bf16x8*)(Lds + aoff[mi]);
#pragma unroll
  for (int ni = 0; ni < 4; ++ni) bfr[ni] = *(const bf16x8*)(Lds + boff[ni]);

  for (int tt = 0; tt < NT; ++tt) {
    if (tt + 2 < NT) stage(tt + 2);
    __builtin_amdgcn_s_setprio(1);
#pragma unroll
    for (int mi = 0; mi < 4; ++mi)
#pragma unroll
      for (int ni = 0; ni < 4; ++ni)
        acc[mi][ni] = __builtin_amdgcn_mfma_f32_16x16x32_bf16(af[mi], bfr[ni], acc[mi][ni], 0, 0, 0);
    __builtin_amdgcn_s_setprio(0);
    if (tt + 1 < NT) {
      if (tt + 2 < NT) asm volatile("s_waitcnt vmcnt(3)" ::: "memory");
      else             asm volatile("s_waitcnt vmcnt(0)" ::: "memory");
      __builtin_amdgcn_s_barrier();
      __builtin_amdgcn_sched_barrier(0);
      const char* S = Lds + ((tt + 1) % 3) * 24576;
#pragma unroll
      for (int mi = 0; mi < 4; ++mi) af[mi]  = *(const bf16x8*)(S + aoff[mi]);
#pragma unroll
      for (int ni = 0; ni < 4; ++ni) bfr[ni] = *(const bf16x8*)(S + boff[ni]);
    }
  }

  const int roff = (l >> 4) << 2;
  const int row0 = bm * 128 + wr * 64 + roff;
  const int col0 = bn * 256 + wc * 64 + lr;
  float bv[4];
#pragma unroll
  for (int ni = 0; ni < 4; ++ni) bv[ni] = bias ? bias[col0 + ni * 16] : 0.0f;

  if (MODE == 1) {
#pragma unroll
    for (int mi = 0; mi < 4; ++mi) {
#pragma unroll
      for (int r = 0; r < 4; ++r) {
        const long rb = (long)(row0 + mi * 16 + r) * N;
#pragma unroll
        for (int ni = 0; ni < 4; ++ni)
          ((float*)Cp)[rb + col0 + ni * 16] = acc[mi][ni][r] + bv[ni];
      }
    }
  } else {
    const float C1 = 0.08838834764831845f * 1.4426950408889634f;  // 1/sqrt(128)*log2e
    const int sec = col0 >> 11;          // block-uniform: 0=q, 1=k, 2=v
    const int cq0 = col0 & 2047;
    const int parity = col0 & 1;         // = lr&1
    int hh[4], dd[4], jj[4];
#pragma unroll
    for (int ni = 0; ni < 4; ++ni) {
      const int c = cq0 + ni * 16;
      hh[ni] = c >> 7;
      dd[ni] = c & 127;                  // V: true d; Q/K: interleaved d' = own col
      jj[ni] = dd[ni] >> 1;              // RoPE pair index (table)
    }
    if (sec == 2) {
      // direct-transposed V: acc[mi][ni][0..3] = 4 consecutive tt (tt0 % 4 == 0)
#pragma unroll
      for (int mi = 0; mi < 4; ++mi) {
        const int tt0 = row0 + mi * 16;
        const int b = tt0 >> 11, ttl = tt0 & 2047;
#pragma unroll
        for (int ni = 0; ni < 4; ++ni) {
          ushort4 pk;
          pk.x = f2b(acc[mi][ni][0] + bv[ni]);
          pk.y = f2b(acc[mi][ni][1] + bv[ni]);
          pk.z = f2b(acc[mi][ni][2] + bv[ni]);
          pk.w = f2b(acc[mi][ni][3] + bv[ni]);
          *(ushort4*)&Vt[((long)((b << 4) | hh[ni]) * 128 + dd[ni]) * 2048 + ttl] = pk;
        }
      }
    } else {
#pragma unroll
      for (int mi = 0; mi < 4; ++mi) {
#pragma unroll
        for (int r = 0; r < 4; ++r) {
          const int row = row0 + mi * 16 + r;
          const int b = row >> 11, tt = row & 2047;
#pragma unroll
          for (int ni = 0; ni < 4; ++ni) {
            const float val = acc[mi][ni][r] + bv[ni];
            const float pv = __shfl_xor(val, 1, 64);
            const float2 t2 = tab[tt * 64 + jj[ni]];
            // interleaved layout: lane stores at its OWN column dd[ni]
            // even col (x1): x1*cos - x2*sin ; odd col (x2, pv=x1): x1*sin + x2*cos
            const float outv = parity ? fmaf(pv, t2.y, val * t2.x)
                                      : fmaf(val, t2.x, -(pv * t2.y));
            const long addr = ((long)((b << 4) | hh[ni]) * 2048 + tt) * 128 + dd[ni];
            if (sec == 0) Qr[addr] = f2b(outv);
            else          Kr[addr] = f2b(outv * C1);
          }
        }
      }
    }
  }
}

// ---------------- causal flash attention (R14 version, frozen) ----------------
// K dbuf (32KB) + single-V (16KB) = 48KB -> 3 blocks/CU. Swapped QK^T (exp2 domain
// via pre-scaled K; Q/K share an interleaved d-layout — dot product unchanged),
// in-reg softmax/P (cvt_pk+shfl), defer-max.
__global__ __launch_bounds__(256)
void attn_fwd(const unsigned short* __restrict__ Q,
              const unsigned short* __restrict__ Kg,
              const unsigned short* __restrict__ Vt,
              unsigned short* __restrict__ O, int T)
{
  __shared__ __align__(16) unsigned short Ks[2][64 * 128];
  __shared__ __align__(16) unsigned short Vs[128 * 64];
  const int t = threadIdx.x;
  const int w = t >> 6, l = t & 63;
  const int lr = l & 15;
  const int g  = l >> 4;
  const int g16 = g << 4;
  const int sw = (lr & 7) << 4;
  const int bh = blockIdx.x;
  const int qt = (gridDim.y - 1) - blockIdx.y;
  const int q0 = qt * 64 + w * 16;
  const long hbase = (long)bh * T * 128;
  const long hbase2 = hbase * 2;
  const long T2 = (long)T * 2;
  const int roff = g << 2;

  bf16x8 qf[4];
  const unsigned short* Qrow = Q + hbase + (long)(q0 + lr) * 128;
#pragma unroll
  for (int ds = 0; ds < 4; ++ds) qf[ds] = *(const bf16x8*)&Qrow[ds * 32 + (g16 >> 1)];

  f32x4 o[8] = {};
  float m = -INFINITY, lsum = 0.f;

  auto stageK = [&](int kt, int buf) {
#pragma unroll
    for (int c = 0; c < 4; ++c) {
      const int o2 = t * 16 + c * 4096;
      const int krow = o2 >> 8, kcb = o2 & 255;
      GLOAD_LDS16((const char*)Kg + hbase2 + (long)kt * 16384 + krow * 256 + (kcb ^ ((krow & 7) << 4)),
                  (char*)Ks[buf] + o2);
    }
  };
  auto stageV = [&](int kt) {
#pragma unroll
    for (int c = 0; c < 4; ++c) {
      const int o2 = t * 16 + c * 4096;
      const int vrow = o2 >> 7, vcb = o2 & 127;
      GLOAD_LDS16((const char*)Vt + (long)(bh * 128 + vrow) * T2 + (long)kt * 128 + (vcb ^ ((vrow & 7) << 4)),
                  (char*)Vs + o2);
    }
  };

  const int ntile = qt + 1;
  stageK(0, 0);
  stageV(0);
  __syncthreads();

  for (int kt = 0; kt < ntile; ++kt) {
    const int cur = kt & 1;
    if (kt + 1 < ntile) stageK(kt + 1, cur ^ 1);

    const char* KsB = (const char*)Ks[cur];

    // S^T (exp2 domain, K pre-scaled): s[tj] = S[kv = kt*64+tj*16+4g+r][q = q0+lr]
    f32x4 s[4] = {};
    __builtin_amdgcn_s_setprio(1);
#pragma unroll
    for (int tj = 0; tj < 4; ++tj)
#pragma unroll
      for (int ds = 0; ds < 4; ++ds) {
        bf16x8 kf = *(const bf16x8*)(KsB + (tj * 16 + lr) * 256 + ((ds * 64 + g16) ^ sw));
        s[tj] = __builtin_amdgcn_mfma_f32_16x16x32_bf16(kf, qf[ds], s[tj], 0, 0, 0);
      }
    __builtin_amdgcn_s_setprio(0);

    if (kt == qt) {
#pragma unroll
      for (int tj = 0; tj < 4; ++tj)
#pragma unroll
        for (int r = 0; r < 4; ++r)
          if (kt * 64 + tj * 16 + 4 * g + r > q0 + lr) s[tj][r] = -INFINITY;
    }

    float pmax = -INFINITY;
#pragma unroll
    for (int tj = 0; tj < 4; ++tj)
#pragma unroll
      for (int r = 0; r < 4; ++r) pmax = fmaxf(pmax, s[tj][r]);
    pmax = fmaxf(pmax, __shfl_xor(pmax, 16, 64));
    pmax = fmaxf(pmax, __shfl_xor(pmax, 32, 64));

    const bool need = !__all(pmax - m <= 8.0f);
    float corr = 1.0f;
    if (need) {
      const float mn = fmaxf(m, pmax);
      corr = exp2f(m - mn);
      m = mn;
    }

    float p[4][4];
    float rs = 0.f;
#pragma unroll
    for (int tj = 0; tj < 4; ++tj)
#pragma unroll
      for (int r = 0; r < 4; ++r) {
        const float pv = exp2f(s[tj][r] - m);
        p[tj][r] = pv;
        rs += pv;
      }
    rs += __shfl_xor(rs, 16, 64);
    rs += __shfl_xor(rs, 32, 64);
    lsum = lsum * corr + rs;

    unsigned D8[4][2];
#pragma unroll
    for (int tj = 0; tj < 4; ++tj) {
      D8[tj][0] = cvt_pk_bf16(p[tj][0], p[tj][1]);
      D8[tj][1] = cvt_pk_bf16(p[tj][2], p[tj][3]);
    }

    if (need) {
      float corrj[4];
#pragma unroll
      for (int j = 0; j < 4; ++j) corrj[j] = __shfl(corr, roff + j, 64);
#pragma unroll
      for (int nj = 0; nj < 8; ++nj)
#pragma unroll
        for (int j = 0; j < 4; ++j) o[nj][j] *= corrj[j];
    }

    // own V loads landed (4 K-loads may remain in flight); all waves at barrier
    if (kt + 1 < ntile) asm volatile("s_waitcnt vmcnt(4)" ::: "memory");
    else                asm volatile("s_waitcnt vmcnt(0)" ::: "memory");
    __builtin_amdgcn_s_barrier();
    __builtin_amdgcn_sched_barrier(0);

    __builtin_amdgcn_s_setprio(1);
#pragma unroll
    for (int ks = 0; ks < 2; ++ks) {
      union { unsigned u[4]; bf16x8 v; } pfu;
#pragma unroll
      for (int k2 = 0; k2 < 4; ++k2) {
        const int src = lr | ((2 * (g & 1) + (k2 >> 1)) << 4);
        const unsigned dwA = __shfl(D8[2 * ks][k2 & 1], src, 64);
        const unsigned dwB = __shfl(D8[2 * ks + 1][k2 & 1], src, 64);
        pfu.u[k2] = (g & 2) ? dwB : dwA;
      }
#pragma unroll
      for (int nj = 0; nj < 8; ++nj) {
        bf16x8 vf = *(const bf16x8*)((const char*)Vs + (nj * 16 + lr) * 128 + ((ks * 64 + g16) ^ sw));
        o[nj] = __builtin_amdgcn_mfma_f32_16x16x32_bf16(pfu.v, vf, o[nj], 0, 0, 0);
      }
    }
    __builtin_amdgcn_s_setprio(0);

    __syncthreads();                       // all waves done with Vs + Ks[cur]
    if (kt + 1 < ntile) stageV(kt + 1);    // safe overwrite of single V buffer
  }

  const float inv = 1.0f / lsum;
  float invj[4];
#pragma unroll
  for (int j = 0; j < 4; ++j) invj[j] = __shfl(inv, roff + j, 64);
  const int b = bh >> 4, h = bh & 15;
#pragma unroll
  for (int nj = 0; nj < 8; ++nj)
#pragma unroll
    for (int j = 0; j < 4; ++j) {
      const int q = q0 + roff + j;
      const int d = nj * 16 + lr;
      O[(long)(b * T + q) * 2048 + h * 128 + d] = f2b(o[nj][j] * invj[j]);
    }
}

// ---------------- launch ----------------
extern "C" void kernel_launch(void* const* d_in, const int* in_sizes, int n_in,
                              void* d_out, int out_size, void* d_ws, size_t ws_size,
                              hipStream_t stream)
{
  const int B = 2, T = 2048, C = 2048;
  const int M = B * T;        // 4096
  const int N1 = 3 * C;       // 6144
  const float* x    = (const float*)d_in[0];
  const float* Wqkv = (const float*)d_in[1];
  const float* bqkv = (const float*)d_in[2];
  const float* Wout = (const float*)d_in[3];
  const float* bout = (const float*)d_in[4];
  float* out = (float*)d_out;

  char* p = (char*)d_ws;
  unsigned short* xb    = (unsigned short*)p; p += (size_t)M * C * 2;
  unsigned short* wqkvb = (unsigned short*)p; p += (size_t)N1 * C * 2;
  unsigned short* woutb = (unsigned short*)p; p += (size_t)C * C * 2;
  unsigned short* Qr    = (unsigned short*)p; p += (size_t)M * C * 2;
  unsigned short* Kr    = (unsigned short*)p; p += (size_t)M * C * 2;
  unsigned short* Vt    = (unsigned short*)p; p += (size_t)M * C * 2;
  float2*         tab   = (float2*)p;         p += (size_t)T * 64 * sizeof(float2);
  unsigned short* Ob    = xb;  // xb dead after QKV GEMM

  // cast (24576 blocks) + rope table fill (512 blocks)
  cast3_kernel<<<24576 + 512, 256, 0, stream>>>(x, Wqkv, Wout, xb, tab);

  // QKV GEMM with fused table-RoPE/scale + direct-transposed V epilogue
  gemm128<2><<<dim3((M / 128) * (N1 / 256)), 512, 0, stream>>>(
      xb, wqkvb, bqkv, nullptr, Qr, Kr, Vt, tab, M, N1, C);

  attn_fwd<<<dim3(32, T / 64), 256, 0, stream>>>(Qr, Kr, Vt, Ob, T);

  gemm128<1><<<dim3((M / 128) * (C / 256)), 512, 0, stream>>>(
      Ob, woutb, bout, out, nullptr, nullptr, nullptr, nullptr, M, C, C);
}

// Round 19
// 261.615 us; speedup vs baseline: 1.3819x; 1.0201x over previous
//
#include <hip/hip_runtime.h>
#include <hip/hip_bf16.h>

typedef __attribute__((ext_vector_type(8))) short bf16x8;
typedef __attribute__((ext_vector_type(4))) float f32x4;

#define GLOAD_LDS16(gptr, lptr) \
  __builtin_amdgcn_global_load_lds((const __attribute__((address_space(1))) void*)(gptr), \
                                   (__attribute__((address_space(3))) void*)(lptr), 16, 0, 0)

__device__ __forceinline__ unsigned short f2b(float f) {
  union { float f; unsigned u; } x; x.f = f;
  unsigned r = x.u + 0x7fffu + ((x.u >> 16) & 1u);
  return (unsigned short)(r >> 16);
}
__device__ __forceinline__ float b2f(unsigned short u) {
  union { unsigned u; float f; } x; x.u = ((unsigned)u) << 16;
  return x.f;
}
__device__ __forceinline__ unsigned cvt_pk_bf16(float lo, float hi) {
  unsigned d;
  asm("v_cvt_pk_bf16_f32 %0, %1, %2" : "=v"(d) : "v"(lo), "v"(hi));
  return d;
}

// ------- fused fp32->bf16 cast (x|W_qkv|W_out) + RoPE cos/sin table fill -------
__global__ void cast3_kernel(const float* __restrict__ x,
                             const float* __restrict__ wq,
                             const float* __restrict__ wo,
                             unsigned short* __restrict__ out,
                             float2* __restrict__ tab)
{
  const long n1 = 8388608L;    // M*C
  const long n2 = 20971520L;   // + N1*C
  const long nc = 25165824L;   // + C*C
  const long tid = (long)blockIdx.x * 256 + threadIdx.x;
  const long i = tid * 4;
  if (i < nc) {
    const float* src; long off;
    if (i < n1)      { src = x;  off = i; }
    else if (i < n2) { src = wq; off = i - n1; }
    else             { src = wo; off = i - n2; }
    const float4 v = *(const float4*)(src + off);
    ushort4 r;
    r.x = f2b(v.x); r.y = f2b(v.y); r.z = f2b(v.z); r.w = f2b(v.w);
    *(ushort4*)(out + i) = r;
  } else {
    const int k = (int)(tid - nc / 4);   // 0..131071 = [tt(11)|j(6)]
    const int tt = k >> 6, j = k & 63;
    const float inv = exp2f(-(float)j * 0.2076205059304602f);
    float sn, cs;
    sincosf((float)tt * inv, &sn, &cs);
    tab[k] = make_float2(cs, sn);
  }
}

// ---------------- GEMM 128x256, BK=32, 3-slot LDS (R8 core, frozen) ----------------
// MODE 1: plain f32 C write (out projection).
// MODE 2: fused QKV epilogue — table-based RoPE for q/k (interleaved d-layout),
//         direct-transposed V store.
// wg->(bm,bn) is bm-INNER: each XCD's resident blocks span few bn (B-panels
// L2-fit) while small A-panels stream — cuts B re-fetch thrash.
template<int MODE>
__global__ __launch_bounds__(512, 4)
void gemm128(const unsigned short* __restrict__ A,
             const unsigned short* __restrict__ Bm,
             const float* __restrict__ bias,
             void* __restrict__ Cp,
             unsigned short* __restrict__ Qr,
             unsigned short* __restrict__ Kr,
             unsigned short* __restrict__ Vt,
             const float2* __restrict__ tab,
             int M, int N, int K)
{
  __shared__ __align__(16) char Lds[73728];   // 3 slots x (A 8KB | B 16KB)
  const int t  = threadIdx.x;
  const int l  = t & 63;
  const int w  = t >> 6;
  const int lr = l & 15;
  const int lkb = (l >> 4) << 4;
  const int wr = w >> 2;
  const int wc = w & 3;

  const int nwg = gridDim.x;
  const int wg  = (blockIdx.x & 7) * (nwg >> 3) + (blockIdx.x >> 3);
  const int NBM = M >> 7;
  const int bm = wg % NBM, bn = wg / NBM;   // bm-inner (B-panel L2 locality)

  const long K2 = (long)K * 2;
  const char* Ab = (const char*)A  + (long)(bm * 128) * K2;
  const char* Bb = (const char*)Bm + (long)(bn * 256) * K2;

  auto swz = [](int a) -> int { return a ^ (((a >> 7) & 3) << 4); };

  const int t16 = t << 4;
  const int da  = swz(t16);
  const long sa = (long)(da >> 6) * K2 + (da & 63);
  const int db0 = swz(t16), db1 = swz(8192 + t16);
  const long sb0 = (long)(db0 >> 6) * K2 + (db0 & 63);
  const long sb1 = (long)(db1 >> 6) * K2 + (db1 & 63);

  auto stage = [&](int g) {
    char* S = Lds + (g % 3) * 24576;
    const char* As = Ab + (long)g * 64;
    const char* Bs = Bb + (long)g * 64;
    GLOAD_LDS16(As + sa,  S + t16);
    GLOAD_LDS16(Bs + sb0, S + 8192 + t16);
    GLOAD_LDS16(Bs + sb1, S + 16384 + t16);
  };

  int aoff[4], boff[4];
#pragma unroll
  for (int mi = 0; mi < 4; ++mi) {
    const int a = ((wr * 64 + mi * 16 + lr) << 6) | lkb;
    aoff[mi] = swz(a);
  }
#pragma unroll
  for (int ni = 0; ni < 4; ++ni) {
    const int a = ((wc * 64 + ni * 16 + lr) << 6) | lkb;
    boff[ni] = 8192 + swz(a);
  }

  f32x4 acc[4][4] = {};
  const int NT = K >> 5;
  bf16x8 af[4], bfr[4];

  stage(0); stage(1);
  asm volatile("s_waitcnt vmcnt(3)" ::: "memory");
  __builtin_amdgcn_s_barrier();
  __builtin_amdgcn_sched_barrier(0);
#pragma unroll
  for (int mi = 0; mi < 4; ++mi) af[mi]  = *(const bf16x8*)(Lds + aoff[mi]);
#pragma unroll
  for (int ni = 0; ni < 4; ++ni) bfr[ni] = *(const bf16x8*)(Lds + boff[ni]);

  for (int tt = 0; tt < NT; ++tt) {
    if (tt + 2 < NT) stage(tt + 2);
    __builtin_amdgcn_s_setprio(1);
#pragma unroll
    for (int mi = 0; mi < 4; ++mi)
#pragma unroll
      for (int ni = 0; ni < 4; ++ni)
        acc[mi][ni] = __builtin_amdgcn_mfma_f32_16x16x32_bf16(af[mi], bfr[ni], acc[mi][ni], 0, 0, 0);
    __builtin_amdgcn_s_setprio(0);
    if (tt + 1 < NT) {
      if (tt + 2 < NT) asm volatile("s_waitcnt vmcnt(3)" ::: "memory");
      else             asm volatile("s_waitcnt vmcnt(0)" ::: "memory");
      __builtin_amdgcn_s_barrier();
      __builtin_amdgcn_sched_barrier(0);
      const char* S = Lds + ((tt + 1) % 3) * 24576;
#pragma unroll
      for (int mi = 0; mi < 4; ++mi) af[mi]  = *(const bf16x8*)(S + aoff[mi]);
#pragma unroll
      for (int ni = 0; ni < 4; ++ni) bfr[ni] = *(const bf16x8*)(S + boff[ni]);
    }
  }

  const int roff = (l >> 4) << 2;
  const int row0 = bm * 128 + wr * 64 + roff;
  const int col0 = bn * 256 + wc * 64 + lr;
  float bv[4];
#pragma unroll
  for (int ni = 0; ni < 4; ++ni) bv[ni] = bias ? bias[col0 + ni * 16] : 0.0f;

  if (MODE == 1) {
#pragma unroll
    for (int mi = 0; mi < 4; ++mi) {
#pragma unroll
      for (int r = 0; r < 4; ++r) {
        const long rb = (long)(row0 + mi * 16 + r) * N;
#pragma unroll
        for (int ni = 0; ni < 4; ++ni)
          ((float*)Cp)[rb + col0 + ni * 16] = acc[mi][ni][r] + bv[ni];
      }
    }
  } else {
    const float C1 = 0.08838834764831845f * 1.4426950408889634f;  // 1/sqrt(128)*log2e
    const int sec = col0 >> 11;          // block-uniform: 0=q, 1=k, 2=v
    const int cq0 = col0 & 2047;
    const int parity = col0 & 1;         // = lr&1
    int hh[4], dd[4], jj[4];
#pragma unroll
    for (int ni = 0; ni < 4; ++ni) {
      const int c = cq0 + ni * 16;
      hh[ni] = c >> 7;
      dd[ni] = c & 127;                  // V: true d; Q/K: interleaved d' = own col
      jj[ni] = dd[ni] >> 1;              // RoPE pair index (table)
    }
    if (sec == 2) {
      // direct-transposed V: acc[mi][ni][0..3] = 4 consecutive tt (tt0 % 4 == 0)
#pragma unroll
      for (int mi = 0; mi < 4; ++mi) {
        const int tt0 = row0 + mi * 16;
        const int b = tt0 >> 11, ttl = tt0 & 2047;
#pragma unroll
        for (int ni = 0; ni < 4; ++ni) {
          ushort4 pk;
          pk.x = f2b(acc[mi][ni][0] + bv[ni]);
          pk.y = f2b(acc[mi][ni][1] + bv[ni]);
          pk.z = f2b(acc[mi][ni][2] + bv[ni]);
          pk.w = f2b(acc[mi][ni][3] + bv[ni]);
          *(ushort4*)&Vt[((long)((b << 4) | hh[ni]) * 128 + dd[ni]) * 2048 + ttl] = pk;
        }
      }
    } else {
#pragma unroll
      for (int mi = 0; mi < 4; ++mi) {
#pragma unroll
        for (int r = 0; r < 4; ++r) {
          const int row = row0 + mi * 16 + r;
          const int b = row >> 11, tt = row & 2047;
#pragma unroll
          for (int ni = 0; ni < 4; ++ni) {
            const float val = acc[mi][ni][r] + bv[ni];
            const float pv = __shfl_xor(val, 1, 64);
            const float2 t2 = tab[tt * 64 + jj[ni]];
            // interleaved layout: lane stores at its OWN column dd[ni]
            const float outv = parity ? fmaf(pv, t2.y, val * t2.x)
                                      : fmaf(val, t2.x, -(pv * t2.y));
            const long addr = ((long)((b << 4) | hh[ni]) * 2048 + tt) * 128 + dd[ni];
            if (sec == 0) Qr[addr] = f2b(outv);
            else          Kr[addr] = f2b(outv * C1);
          }
        }
      }
    }
  }
}

// ---------------- causal flash attention (R14 version, frozen) ----------------
__global__ __launch_bounds__(256)
void attn_fwd(const unsigned short* __restrict__ Q,
              const unsigned short* __restrict__ Kg,
              const unsigned short* __restrict__ Vt,
              unsigned short* __restrict__ O, int T)
{
  __shared__ __align__(16) unsigned short Ks[2][64 * 128];
  __shared__ __align__(16) unsigned short Vs[128 * 64];
  const int t = threadIdx.x;
  const int w = t >> 6, l = t & 63;
  const int lr = l & 15;
  const int g  = l >> 4;
  const int g16 = g << 4;
  const int sw = (lr & 7) << 4;
  const int bh = blockIdx.x;
  const int qt = (gridDim.y - 1) - blockIdx.y;
  const int q0 = qt * 64 + w * 16;
  const long hbase = (long)bh * T * 128;
  const long hbase2 = hbase * 2;
  const long T2 = (long)T * 2;
  const int roff = g << 2;

  bf16x8 qf[4];
  const unsigned short* Qrow = Q + hbase + (long)(q0 + lr) * 128;
#pragma unroll
  for (int ds = 0; ds < 4; ++ds) qf[ds] = *(const bf16x8*)&Qrow[ds * 32 + (g16 >> 1)];

  f32x4 o[8] = {};
  float m = -INFINITY, lsum = 0.f;

  auto stageK = [&](int kt, int buf) {
#pragma unroll
    for (int c = 0; c < 4; ++c) {
      const int o2 = t * 16 + c * 4096;
      const int krow = o2 >> 8, kcb = o2 & 255;
      GLOAD_LDS16((const char*)Kg + hbase2 + (long)kt * 16384 + krow * 256 + (kcb ^ ((krow & 7) << 4)),
                  (char*)Ks[buf] + o2);
    }
  };
  auto stageV = [&](int kt) {
#pragma unroll
    for (int c = 0; c < 4; ++c) {
      const int o2 = t * 16 + c * 4096;
      const int vrow = o2 >> 7, vcb = o2 & 127;
      GLOAD_LDS16((const char*)Vt + (long)(bh * 128 + vrow) * T2 + (long)kt * 128 + (vcb ^ ((vrow & 7) << 4)),
                  (char*)Vs + o2);
    }
  };

  const int ntile = qt + 1;
  stageK(0, 0);
  stageV(0);
  __syncthreads();

  for (int kt = 0; kt < ntile; ++kt) {
    const int cur = kt & 1;
    if (kt + 1 < ntile) stageK(kt + 1, cur ^ 1);

    const char* KsB = (const char*)Ks[cur];

    f32x4 s[4] = {};
    __builtin_amdgcn_s_setprio(1);
#pragma unroll
    for (int tj = 0; tj < 4; ++tj)
#pragma unroll
      for (int ds = 0; ds < 4; ++ds) {
        bf16x8 kf = *(const bf16x8*)(KsB + (tj * 16 + lr) * 256 + ((ds * 64 + g16) ^ sw));
        s[tj] = __builtin_amdgcn_mfma_f32_16x16x32_bf16(kf, qf[ds], s[tj], 0, 0, 0);
      }
    __builtin_amdgcn_s_setprio(0);

    if (kt == qt) {
#pragma unroll
      for (int tj = 0; tj < 4; ++tj)
#pragma unroll
        for (int r = 0; r < 4; ++r)
          if (kt * 64 + tj * 16 + 4 * g + r > q0 + lr) s[tj][r] = -INFINITY;
    }

    float pmax = -INFINITY;
#pragma unroll
    for (int tj = 0; tj < 4; ++tj)
#pragma unroll
      for (int r = 0; r < 4; ++r) pmax = fmaxf(pmax, s[tj][r]);
    pmax = fmaxf(pmax, __shfl_xor(pmax, 16, 64));
    pmax = fmaxf(pmax, __shfl_xor(pmax, 32, 64));

    const bool need = !__all(pmax - m <= 8.0f);
    float corr = 1.0f;
    if (need) {
      const float mn = fmaxf(m, pmax);
      corr = exp2f(m - mn);
      m = mn;
    }

    float p[4][4];
    float rs = 0.f;
#pragma unroll
    for (int tj = 0; tj < 4; ++tj)
#pragma unroll
      for (int r = 0; r < 4; ++r) {
        const float pv = exp2f(s[tj][r] - m);
        p[tj][r] = pv;
        rs += pv;
      }
    rs += __shfl_xor(rs, 16, 64);
    rs += __shfl_xor(rs, 32, 64);
    lsum = lsum * corr + rs;

    unsigned D8[4][2];
#pragma unroll
    for (int tj = 0; tj < 4; ++tj) {
      D8[tj][0] = cvt_pk_bf16(p[tj][0], p[tj][1]);
      D8[tj][1] = cvt_pk_bf16(p[tj][2], p[tj][3]);
    }

    if (need) {
      float corrj[4];
#pragma unroll
      for (int j = 0; j < 4; ++j) corrj[j] = __shfl(corr, roff + j, 64);
#pragma unroll
      for (int nj = 0; nj < 8; ++nj)
#pragma unroll
        for (int j = 0; j < 4; ++j) o[nj][j] *= corrj[j];
    }

    if (kt + 1 < ntile) asm volatile("s_waitcnt vmcnt(4)" ::: "memory");
    else                asm volatile("s_waitcnt vmcnt(0)" ::: "memory");
    __builtin_amdgcn_s_barrier();
    __builtin_amdgcn_sched_barrier(0);

    __builtin_amdgcn_s_setprio(1);
#pragma unroll
    for (int ks = 0; ks < 2; ++ks) {
      union { unsigned u[4]; bf16x8 v; } pfu;
#pragma unroll
      for (int k2 = 0; k2 < 4; ++k2) {
        const int src = lr | ((2 * (g & 1) + (k2 >> 1)) << 4);
        const unsigned dwA = __shfl(D8[2 * ks][k2 & 1], src, 64);
        const unsigned dwB = __shfl(D8[2 * ks + 1][k2 & 1], src, 64);
        pfu.u[k2] = (g & 2) ? dwB : dwA;
      }
#pragma unroll
      for (int nj = 0; nj < 8; ++nj) {
        bf16x8 vf = *(const bf16x8*)((const char*)Vs + (nj * 16 + lr) * 128 + ((ks * 64 + g16) ^ sw));
        o[nj] = __builtin_amdgcn_mfma_f32_16x16x32_bf16(pfu.v, vf, o[nj], 0, 0, 0);
      }
    }
    __builtin_amdgcn_s_setprio(0);

    __syncthreads();
    if (kt + 1 < ntile) stageV(kt + 1);
  }

  const float inv = 1.0f / lsum;
  float invj[4];
#pragma unroll
  for (int j = 0; j < 4; ++j) invj[j] = __shfl(inv, roff + j, 64);
  const int b = bh >> 4, h = bh & 15;
#pragma unroll
  for (int nj = 0; nj < 8; ++nj)
#pragma unroll
    for (int j = 0; j < 4; ++j) {
      const int q = q0 + roff + j;
      const int d = nj * 16 + lr;
      O[(long)(b * T + q) * 2048 + h * 128 + d] = f2b(o[nj][j] * invj[j]);
    }
}

// ---------------- launch ----------------
extern "C" void kernel_launch(void* const* d_in, const int* in_sizes, int n_in,
                              void* d_out, int out_size, void* d_ws, size_t ws_size,
                              hipStream_t stream)
{
  const int B = 2, T = 2048, C = 2048;
  const int M = B * T;        // 4096
  const int N1 = 3 * C;       // 6144
  const float* x    = (const float*)d_in[0];
  const float* Wqkv = (const float*)d_in[1];
  const float* bqkv = (const float*)d_in[2];
  const float* Wout = (const float*)d_in[3];
  const float* bout = (const float*)d_in[4];
  float* out = (float*)d_out;

  char* p = (char*)d_ws;
  unsigned short* xb    = (unsigned short*)p; p += (size_t)M * C * 2;
  unsigned short* wqkvb = (unsigned short*)p; p += (size_t)N1 * C * 2;
  unsigned short* woutb = (unsigned short*)p; p += (size_t)C * C * 2;
  unsigned short* Qr    = (unsigned short*)p; p += (size_t)M * C * 2;
  unsigned short* Kr    = (unsigned short*)p; p += (size_t)M * C * 2;
  unsigned short* Vt    = (unsigned short*)p; p += (size_t)M * C * 2;
  float2*         tab   = (float2*)p;         p += (size_t)T * 64 * sizeof(float2);
  unsigned short* Ob    = xb;  // xb dead after QKV GEMM

  // cast (24576 blocks) + rope table fill (512 blocks)
  cast3_kernel<<<24576 + 512, 256, 0, stream>>>(x, Wqkv, Wout, xb, tab);

  // QKV GEMM with fused table-RoPE/scale + direct-transposed V epilogue
  gemm128<2><<<dim3((M / 128) * (N1 / 256)), 512, 0, stream>>>(
      xb, wqkvb, bqkv, nullptr, Qr, Kr, Vt, tab, M, N1, C);

  attn_fwd<<<dim3(32, T / 64), 256, 0, stream>>>(Qr, Kr, Vt, Ob, T);

  gemm128<1><<<dim3((M / 128) * (C / 256)), 512, 0, stream>>>(
      Ob, woutb, bout, out, nullptr, nullptr, nullptr, nullptr, M, C, C);
}